// Round 7
// baseline (61.150 us; speedup 1.0000x reference)
//
#include <hip/hip_runtime.h>

#define LSTEPS 64
#define NF 512
#define MB 2048
#define CSTRIDE 256           // padded per-step pair stride for cA/cB (float4-pairs)
#define PL (NF * NF)          // bf16 elements per 512x512 plane
#define LDT 72

typedef __attribute__((ext_vector_type(8))) short bf16x8;
typedef __attribute__((ext_vector_type(4))) float f32x4;
typedef __attribute__((ext_vector_type(4))) int i32x4;

__device__ __forceinline__ float2 cmul(float2 a, float2 b) {
  return make_float2(fmaf(a.x, b.x, -(a.y * b.y)), fmaf(a.x, b.y, a.y * b.x));
}
__device__ __forceinline__ float2 cfma(float2 a, float2 b, float2 c) {
  return make_float2(fmaf(a.x, b.x, fmaf(-a.y, b.y, c.x)),
                     fmaf(a.x, b.y, fmaf(a.y, b.x, c.y)));
}
__device__ __forceinline__ unsigned short f2bf(float f) {
  union { float f; unsigned u; } v; v.f = f;
  unsigned r = v.u + 0x7FFF + ((v.u >> 16) & 1);
  return (unsigned short)(r >> 16);
}

// ---------------- K1: coeffs (incl. zero-fill of cB pair 255) + X->bf16 planes ----------------
__global__ __launch_bounds__(256) void prep_kernel(
    const float* __restrict__ a0, const float* __restrict__ a1,
    const float* __restrict__ b0, const float* __restrict__ b1,
    const float4* __restrict__ Xf,
    float4* __restrict__ cA, float4* __restrict__ cB,
    unsigned short* __restrict__ Xr, unsigned short* __restrict__ Xi)
{
  const int bid = blockIdx.x, tid = threadIdx.x;
  if (bid < 64) {
    const int l = bid;
    {
      float ang0 = a0[l * 256 + tid], ang1 = a1[l * 256 + tid];
      float se, ce, st, ct;
      sincosf(ang0, &se, &ce);
      sincosf(ang1, &st, &ct);
      float2 ephi = make_float2(ce, se);
      float2 tt = make_float2(0.5f * (ct - 1.0f), 0.5f * st);
      float2 uu = make_float2(0.5f * (ct + 1.0f), 0.5f * st);
      float2 C1 = cmul(ephi, tt);
      float2 C2 = make_float2(-uu.y, uu.x);
      float2 eu = cmul(ephi, uu);
      float2 C3 = make_float2(-eu.y, eu.x);
      float2 C4 = make_float2(-tt.x, -tt.y);
      float4* dst = cA + (size_t)(l * CSTRIDE + tid) * 2;
      dst[0] = make_float4(C1.x, C1.y, C2.x, C2.y);
      dst[1] = make_float4(C3.x, C3.y, C4.x, C4.y);
    }
    if (tid < 255) {
      float ang0 = b0[l * 255 + tid], ang1 = b1[l * 255 + tid];
      float se, ce, st, ct;
      sincosf(ang0, &se, &ce);
      sincosf(ang1, &st, &ct);
      float2 ephi = make_float2(ce, se);
      float2 tt = make_float2(0.5f * (ct - 1.0f), 0.5f * st);
      float2 uu = make_float2(0.5f * (ct + 1.0f), 0.5f * st);
      float2 C1 = cmul(ephi, tt);
      float2 C2 = make_float2(-uu.y, uu.x);
      float2 eu = cmul(ephi, uu);
      float2 C3 = make_float2(-eu.y, eu.x);
      float2 C4 = make_float2(-tt.x, -tt.y);
      float4* dst = cB + (size_t)(l * CSTRIDE + tid) * 2;
      dst[0] = make_float4(C1.x, C1.y, C2.x, C2.y);
      dst[1] = make_float4(C3.x, C3.y, C4.x, C4.y);
    } else {
      float4* dst = cB + (size_t)(l * CSTRIDE + 255) * 2;
      dst[0] = make_float4(0.f, 0.f, 0.f, 0.f);
      dst[1] = make_float4(0.f, 0.f, 0.f, 0.f);
    }
  } else {
    const int qi = (bid - 64) * 256 + tid;       // 0..262143
    float4 v0 = Xf[(size_t)qi * 2];
    float4 v1 = Xf[(size_t)qi * 2 + 1];
    ushort4 r, im;
    r.x = f2bf(v0.x); im.x = f2bf(v0.y);
    r.y = f2bf(v0.z); im.y = f2bf(v0.w);
    r.z = f2bf(v1.x); im.z = f2bf(v1.y);
    r.w = f2bf(v1.z); im.w = f2bf(v1.w);
    *(ushort4*)(Xr + (size_t)qi * 4) = r;
    *(ushort4*)(Xi + (size_t)qi * 4) = im;
  }
}

// ---------------- K2: 8-step chunk mesh (proven wave-shuffle core, depth 8, exact cone) ----------------
struct MZS { float2 a0, b0, a1, b1; };

__device__ __forceinline__ void mzi_apply(const float4& k0, const float4& k1,
                                          float2& a, float2& b) {
  float2 c1 = make_float2(k0.x, k0.y), c2 = make_float2(k0.z, k0.w);
  float2 c3 = make_float2(k1.x, k1.y), c4 = make_float2(k1.z, k1.w);
  float2 na = cfma(c2, b, cmul(c1, a));
  float2 nb = cfma(c4, b, cmul(c3, a));
  a = na; b = nb;
}
__device__ __forceinline__ float2 mzi_bnd(const float4& k0, const float4& k1,
                                          float2& a, float2 b, bool en) {
  float2 d1 = make_float2(k0.x, k0.y), d2 = make_float2(k0.z, k0.w);
  float2 d3 = make_float2(k1.x, k1.y), d4 = make_float2(k1.z, k1.w);
  float2 na = cfma(d2, b, cmul(d1, a));
  float2 nb = cfma(d4, b, cmul(d3, a));
  if (en) a = na;
  return en ? nb : make_float2(0.f, 0.f);
}
__device__ __forceinline__ void load_bank(float4 (&K)[8],
    const float4* __restrict__ cA, const float4* __restrict__ cB, int l, int q0)
{
  const float4* pa = cA + (size_t)l * (CSTRIDE * 2) + (size_t)q0 * 2;
  const float4* pb = cB + (size_t)l * (CSTRIDE * 2) + (size_t)q0 * 2;
  K[0] = pa[0]; K[1] = pa[1]; K[2] = pa[2]; K[3] = pa[3];
  K[4] = pb[0]; K[5] = pb[1]; K[6] = pb[2]; K[7] = pb[3];
}
__device__ __forceinline__ void step_state(const float4 (&K)[8], int L, bool hasBnd,
                                           MZS& s)
{
  mzi_apply(K[0], K[1], s.a0, s.b0);
  mzi_apply(K[2], K[3], s.a1, s.b1);
  float xnx = __shfl_down(s.a0.x, 1);
  float xny = __shfl_down(s.a0.y, 1);
  float2 xn = (L == 63) ? make_float2(0.f, 0.f) : make_float2(xnx, xny);
  float2 nbo = mzi_bnd(K[6], K[7], s.b1, xn, hasBnd);
  mzi_apply(K[4], K[5], s.b0, s.a1);
  float px = __shfl_up(nbo.x, 1);
  float py = __shfl_up(nbo.y, 1);
  if (L > 0) s.a0 = make_float2(px, py);
}

__global__ __launch_bounds__(64) void chunk_mesh(
    const float4* __restrict__ cA, const float4* __restrict__ cB,
    unsigned short* __restrict__ Cbase)
{
  const int bid = blockIdx.x;                 // 0..2047
  const int m = bid >> 8;                     // chunk 0..7 (steps 8m..8m+7)
  const int cb = bid & 255;
  const int c = (cb & 7) * 32 + (cb >> 3);    // bijective XCD swizzle
  const int L = threadIdx.x;
  int ws = c - 63; ws = ws < 0 ? 0 : (ws > 128 ? 128 : ws);
  const int q0 = ws + 2 * L, q1 = q0 + 1;
  const bool hasBnd = (q1 < 255);

  MZS s0, s1;   // columns j0=2c (impulse on a) and j1=2c+1 (impulse on b)
  s0.a0 = make_float2((q0 == c) ? 1.f : 0.f, 0.f);
  s0.b0 = make_float2(0.f, 0.f);
  s0.a1 = make_float2((q1 == c) ? 1.f : 0.f, 0.f);
  s0.b1 = make_float2(0.f, 0.f);
  s1.a0 = make_float2(0.f, 0.f);
  s1.b0 = make_float2((q0 == c) ? 1.f : 0.f, 0.f);
  s1.a1 = make_float2(0.f, 0.f);
  s1.b1 = make_float2((q1 == c) ? 1.f : 0.f, 0.f);

  const int l0 = m * 8;
  float4 K0[8], K1[8], K2[8];
  load_bank(K0, cA, cB, l0 + 0, q0);
  load_bank(K1, cA, cB, l0 + 1, q0);
  load_bank(K2, cA, cB, l0 + 2, q0);

  step_state(K0, L, hasBnd, s0); step_state(K0, L, hasBnd, s1);
  load_bank(K0, cA, cB, l0 + 3, q0);
  step_state(K1, L, hasBnd, s0); step_state(K1, L, hasBnd, s1);
  load_bank(K1, cA, cB, l0 + 4, q0);
  step_state(K2, L, hasBnd, s0); step_state(K2, L, hasBnd, s1);
  load_bank(K2, cA, cB, l0 + 5, q0);
  step_state(K0, L, hasBnd, s0); step_state(K0, L, hasBnd, s1);
  load_bank(K0, cA, cB, l0 + 6, q0);
  step_state(K1, L, hasBnd, s0); step_state(K1, L, hasBnd, s1);
  load_bank(K1, cA, cB, l0 + 7, q0);
  step_state(K2, L, hasBnd, s0); step_state(K2, L, hasBnd, s1);
  step_state(K0, L, hasBnd, s0); step_state(K0, L, hasBnd, s1);
  step_state(K1, L, hasBnd, s0); step_state(K1, L, hasBnd, s1);   // 8 steps total

  // ---- write chunk m: normal planes C[i][j] (packed 2-col) + transposed planes C^T[j][i] ----
  unsigned short* Cn_r = Cbase + (size_t)m * 4 * PL;
  unsigned short* Cn_i = Cn_r + PL;
  unsigned short* Ct_r = Cn_r + 2 * PL;
  unsigned short* Ct_i = Cn_r + 3 * PL;
  unsigned* nr32 = (unsigned*)Cn_r;
  unsigned* ni32 = (unsigned*)Cn_i;

  const int rows[4] = {2 * q0, 2 * q0 + 1, 2 * q1, 2 * q1 + 1};
  const float2 v0[4] = {s0.a0, s0.b0, s0.a1, s0.b1};
  const float2 v1[4] = {s1.a0, s1.b0, s1.a1, s1.b1};
  // normal planes: in-window values + zero rows (R6-proven pattern)
#pragma unroll
  for (int e = 0; e < 4; ++e) {
    unsigned pr = (unsigned)f2bf(v0[e].x) | ((unsigned)f2bf(v1[e].x) << 16);
    unsigned pi = (unsigned)f2bf(v0[e].y) | ((unsigned)f2bf(v1[e].y) << 16);
    nr32[(size_t)rows[e] * (NF / 2) + c] = pr;
    ni32[(size_t)rows[e] * (NF / 2) + c] = pi;
  }
#pragma unroll
  for (int e = 0; e < 4; ++e) {
    const int row = (2 * ws + 256 + 4 * L + e) & 511;
    nr32[(size_t)row * (NF / 2) + c] = 0u;
    ni32[(size_t)row * (NF / 2) + c] = 0u;
  }
  // transposed planes: rows j0,j1, columns rows[e] (4 consecutive i) + zero columns
  const int j0 = 2 * c, j1 = 2 * c + 1;
  const int i0 = 2 * q0;
  *(ushort2*)&Ct_r[(size_t)j0 * NF + i0]     = make_ushort2(f2bf(v0[0].x), f2bf(v0[1].x));
  *(ushort2*)&Ct_r[(size_t)j0 * NF + i0 + 2] = make_ushort2(f2bf(v0[2].x), f2bf(v0[3].x));
  *(ushort2*)&Ct_i[(size_t)j0 * NF + i0]     = make_ushort2(f2bf(v0[0].y), f2bf(v0[1].y));
  *(ushort2*)&Ct_i[(size_t)j0 * NF + i0 + 2] = make_ushort2(f2bf(v0[2].y), f2bf(v0[3].y));
  *(ushort2*)&Ct_r[(size_t)j1 * NF + i0]     = make_ushort2(f2bf(v1[0].x), f2bf(v1[1].x));
  *(ushort2*)&Ct_r[(size_t)j1 * NF + i0 + 2] = make_ushort2(f2bf(v1[2].x), f2bf(v1[3].x));
  *(ushort2*)&Ct_i[(size_t)j1 * NF + i0]     = make_ushort2(f2bf(v1[0].y), f2bf(v1[1].y));
  *(ushort2*)&Ct_i[(size_t)j1 * NF + i0 + 2] = make_ushort2(f2bf(v1[2].y), f2bf(v1[3].y));
  const int iz = (2 * ws + 256 + 4 * L) & 511;   // even; pairs never straddle
  const int iz2 = (iz + 2) & 511;
  const ushort2 zz = make_ushort2(0, 0);
  *(ushort2*)&Ct_r[(size_t)j0 * NF + iz]  = zz;
  *(ushort2*)&Ct_r[(size_t)j0 * NF + iz2] = zz;
  *(ushort2*)&Ct_i[(size_t)j0 * NF + iz]  = zz;
  *(ushort2*)&Ct_i[(size_t)j0 * NF + iz2] = zz;
  *(ushort2*)&Ct_r[(size_t)j1 * NF + iz]  = zz;
  *(ushort2*)&Ct_r[(size_t)j1 * NF + iz2] = zz;
  *(ushort2*)&Ct_i[(size_t)j1 * NF + iz]  = zz;
  *(ushort2*)&Ct_i[(size_t)j1 * NF + iz2] = zz;
}

// ---------------- K3: banded complex product  W = A·B  via  W^T[j][n] = sum_k B^T[j][k]·A[n][k] ----------------
// X-slot = B^T (tr/ti planes), U-slot = A (nr/ni planes). Output written in BOTH orientations.
__global__ __launch_bounds__(256) void prod_kernel(
    const unsigned short* __restrict__ baseT,   // +z*zStrT -> [tr, ti]
    const unsigned short* __restrict__ baseN,   // +z*zStrN -> [nr, ni]
    unsigned short* __restrict__ baseW,         // +z*4PL   -> [nr, ni, tr, ti]
    int zStrT, int zStrN, int hwA, int hwB)
{
  __shared__ __align__(16) unsigned short Ars[32][LDT];
  __shared__ __align__(16) unsigned short Ais[32][LDT];
  __shared__ __align__(16) unsigned short Brs[64][LDT];
  __shared__ __align__(16) unsigned short Bis[64][LDT];

  const int z = blockIdx.z;
  const unsigned short* XT_r = baseT + (size_t)z * zStrT;
  const unsigned short* XT_i = XT_r + PL;
  const unsigned short* UN_r = baseN + (size_t)z * zStrN;
  const unsigned short* UN_i = UN_r + PL;
  unsigned short* Wnr = baseW + (size_t)z * 4 * PL;
  unsigned short* Wni = Wnr + PL;
  unsigned short* Wtr = Wnr + 2 * PL;
  unsigned short* Wti = Wnr + 3 * PL;

  const int tid = threadIdx.x;
  const int w = tid >> 6, wm = w & 1, wn = w >> 1;
  const int lane = tid & 63;
  const int bm = blockIdx.x * 32;   // j-tile
  const int bn = blockIdx.y * 64;   // n-tile

  int klo = bn - hwA; { int t = bm - hwB; if (t > klo) klo = t; }
  if (klo < 0) klo = 0; klo &= ~63;
  int khi = bn + 64 + hwA; { int t = bm + 32 + hwB; if (t < khi) khi = t; }
  if (khi > NF) khi = NF; khi = (khi + 63) & ~63;

  f32x4 acc_r[2], acc_i[2];
#pragma unroll
  for (int nf = 0; nf < 2; ++nf) {
    acc_r[nf] = (f32x4){0.f, 0.f, 0.f, 0.f};
    acc_i[nf] = (f32x4){0.f, 0.f, 0.f, 0.f};
  }
  const int sar = tid >> 3, sak = (tid & 7) * 8;
  const int sbr = tid >> 2, sbk = (tid & 3) * 16;

  for (int k0 = klo; k0 < khi; k0 += 64) {
    const uint4* gar = (const uint4*)(XT_r + (size_t)(bm + sar) * NF + k0 + sak);
    const uint4* gai = (const uint4*)(XT_i + (size_t)(bm + sar) * NF + k0 + sak);
    const uint4* gbr = (const uint4*)(UN_r + (size_t)(bn + sbr) * NF + k0 + sbk);
    const uint4* gbi = (const uint4*)(UN_i + (size_t)(bn + sbr) * NF + k0 + sbk);
    uint4 ar = gar[0];
    uint4 ai = gai[0];
    uint4 br0 = gbr[0], br1 = gbr[1];
    uint4 bi0 = gbi[0], bi1 = gbi[1];

    if (k0 > klo) __syncthreads();

    *(uint4*)&Ars[sar][sak]     = ar;
    *(uint4*)&Ais[sar][sak]     = ai;
    *(uint4*)&Brs[sbr][sbk]     = br0;
    *(uint4*)&Brs[sbr][sbk + 8] = br1;
    *(uint4*)&Bis[sbr][sbk]     = bi0;
    *(uint4*)&Bis[sbr][sbk + 8] = bi1;

    __syncthreads();

#pragma unroll
    for (int kk = 0; kk < 2; ++kk) {
      const int ko = kk * 32 + (lane >> 4) * 8;
      bf16x8 afr = *(const bf16x8*)&Ars[wm * 16 + (lane & 15)][ko];
      bf16x8 afi = *(const bf16x8*)&Ais[wm * 16 + (lane & 15)][ko];
      i32x4 neg = (i32x4)afi ^ (int)0x80008000;
      bf16x8 afin = (bf16x8)neg;
#pragma unroll
      for (int nf = 0; nf < 2; ++nf) {
        bf16x8 bfr = *(const bf16x8*)&Brs[wn * 32 + nf * 16 + (lane & 15)][ko];
        bf16x8 bfi = *(const bf16x8*)&Bis[wn * 32 + nf * 16 + (lane & 15)][ko];
        acc_r[nf] = __builtin_amdgcn_mfma_f32_16x16x32_bf16(afr,  bfr, acc_r[nf], 0, 0, 0);
        acc_r[nf] = __builtin_amdgcn_mfma_f32_16x16x32_bf16(afin, bfi, acc_r[nf], 0, 0, 0);
        acc_i[nf] = __builtin_amdgcn_mfma_f32_16x16x32_bf16(afr,  bfi, acc_i[nf], 0, 0, 0);
        acc_i[nf] = __builtin_amdgcn_mfma_f32_16x16x32_bf16(afi,  bfr, acc_i[nf], 0, 0, 0);
      }
    }
  }

  // epilogue: value at (j = dm0+r, n) equals W[n][j]
  const int dn0 = bn + wn * 32 + (lane & 15);
  const int dm0 = bm + wm * 16 + (lane >> 4) * 4;
#pragma unroll
  for (int nf = 0; nf < 2; ++nf) {
    const int n = dn0 + nf * 16;
    ushort4 pr, pi;
    pr.x = f2bf(acc_r[nf][0]); pr.y = f2bf(acc_r[nf][1]);
    pr.z = f2bf(acc_r[nf][2]); pr.w = f2bf(acc_r[nf][3]);
    pi.x = f2bf(acc_i[nf][0]); pi.y = f2bf(acc_i[nf][1]);
    pi.z = f2bf(acc_i[nf][2]); pi.w = f2bf(acc_i[nf][3]);
    *(ushort4*)&Wnr[(size_t)n * NF + dm0] = pr;   // normal: W[n][j], 4 consecutive j
    *(ushort4*)&Wni[(size_t)n * NF + dm0] = pi;
    Wtr[(size_t)(dm0 + 0) * NF + n] = pr.x;       // transposed: W^T[j][n]
    Wtr[(size_t)(dm0 + 1) * NF + n] = pr.y;
    Wtr[(size_t)(dm0 + 2) * NF + n] = pr.z;
    Wtr[(size_t)(dm0 + 3) * NF + n] = pr.w;
    Wti[(size_t)(dm0 + 0) * NF + n] = pi.x;
    Wti[(size_t)(dm0 + 1) * NF + n] = pi.y;
    Wti[(size_t)(dm0 + 2) * NF + n] = pi.z;
    Wti[(size_t)(dm0 + 3) * NF + n] = pi.w;
  }
}

// ---------------- K4: final banded complex GEMM (R6-proven), band margin 136 ----------------
__global__ __launch_bounds__(256) void cgemm_kernel(
    const unsigned short* __restrict__ Xr, const unsigned short* __restrict__ Xi,
    const unsigned short* __restrict__ Ur, const unsigned short* __restrict__ Ui,
    const float* __restrict__ omega,
    float2* __restrict__ Y)
{
  __shared__ __align__(16) unsigned short Ars[32][LDT];
  __shared__ __align__(16) unsigned short Ais[32][LDT];
  __shared__ __align__(16) unsigned short Brs[64][LDT];
  __shared__ __align__(16) unsigned short Bis[64][LDT];

  const int tid = threadIdx.x;
  const int w = tid >> 6, wm = w & 1, wn = w >> 1;
  const int lane = tid & 63;
  const int bm = (blockIdx.x >> 3) * 32;
  const int bn = (blockIdx.x & 7) * 64;

  int klo = bn - 136; if (klo < 0) klo = 0; klo &= ~63;
  int khi = bn + 200; if (khi > NF) khi = NF; khi = (khi + 63) & ~63;

  f32x4 acc_r[2], acc_i[2];
#pragma unroll
  for (int nf = 0; nf < 2; ++nf) {
    acc_r[nf] = (f32x4){0.f, 0.f, 0.f, 0.f};
    acc_i[nf] = (f32x4){0.f, 0.f, 0.f, 0.f};
  }
  const int sar = tid >> 3, sak = (tid & 7) * 8;
  const int sbr = tid >> 2, sbk = (tid & 3) * 16;

  for (int k0 = klo; k0 < khi; k0 += 64) {
    const uint4* gar = (const uint4*)(Xr + (size_t)(bm + sar) * NF + k0 + sak);
    const uint4* gai = (const uint4*)(Xi + (size_t)(bm + sar) * NF + k0 + sak);
    const uint4* gbr = (const uint4*)(Ur + (size_t)(bn + sbr) * NF + k0 + sbk);
    const uint4* gbi = (const uint4*)(Ui + (size_t)(bn + sbr) * NF + k0 + sbk);
    uint4 ar = gar[0];
    uint4 ai = gai[0];
    uint4 br0 = gbr[0], br1 = gbr[1];
    uint4 bi0 = gbi[0], bi1 = gbi[1];

    if (k0 > klo) __syncthreads();

    *(uint4*)&Ars[sar][sak]     = ar;
    *(uint4*)&Ais[sar][sak]     = ai;
    *(uint4*)&Brs[sbr][sbk]     = br0;
    *(uint4*)&Brs[sbr][sbk + 8] = br1;
    *(uint4*)&Bis[sbr][sbk]     = bi0;
    *(uint4*)&Bis[sbr][sbk + 8] = bi1;

    __syncthreads();

#pragma unroll
    for (int kk = 0; kk < 2; ++kk) {
      const int ko = kk * 32 + (lane >> 4) * 8;
      bf16x8 afr = *(const bf16x8*)&Ars[wm * 16 + (lane & 15)][ko];
      bf16x8 afi = *(const bf16x8*)&Ais[wm * 16 + (lane & 15)][ko];
      i32x4 neg = (i32x4)afi ^ (int)0x80008000;
      bf16x8 afin = (bf16x8)neg;
#pragma unroll
      for (int nf = 0; nf < 2; ++nf) {
        bf16x8 bfr = *(const bf16x8*)&Brs[wn * 32 + nf * 16 + (lane & 15)][ko];
        bf16x8 bfi = *(const bf16x8*)&Bis[wn * 32 + nf * 16 + (lane & 15)][ko];
        acc_r[nf] = __builtin_amdgcn_mfma_f32_16x16x32_bf16(afr,  bfr, acc_r[nf], 0, 0, 0);
        acc_r[nf] = __builtin_amdgcn_mfma_f32_16x16x32_bf16(afin, bfi, acc_r[nf], 0, 0, 0);
        acc_i[nf] = __builtin_amdgcn_mfma_f32_16x16x32_bf16(afr,  bfi, acc_i[nf], 0, 0, 0);
        acc_i[nf] = __builtin_amdgcn_mfma_f32_16x16x32_bf16(afi,  bfr, acc_i[nf], 0, 0, 0);
      }
    }
  }

  const int dn0 = bn + wn * 32 + (lane & 15);
  const int dm0 = bm + wm * 16 + (lane >> 4) * 4;
#pragma unroll
  for (int nf = 0; nf < 2; ++nf) {
    const int n = dn0 + nf * 16;
    float sn, cn;
    sincosf(omega[n], &sn, &cn);
#pragma unroll
    for (int r = 0; r < 4; ++r) {
      float yr = acc_r[nf][r], yi = acc_i[nf][r];
      Y[(size_t)(dm0 + r) * NF + n] =
          make_float2(fmaf(yr, cn, -(yi * sn)), fmaf(yr, sn, yi * cn));
    }
  }
}

extern "C" void kernel_launch(void* const* d_in, const int* in_sizes, int n_in,
                              void* d_out, int out_size, void* d_ws, size_t ws_size,
                              hipStream_t stream) {
  const float* cmplx = (const float*)d_in[0];
  const float* a0    = (const float*)d_in[1];
  const float* a1    = (const float*)d_in[2];
  const float* b0    = (const float*)d_in[3];
  const float* b1    = (const float*)d_in[4];
  const float* omega = (const float*)d_in[5];

  size_t off = 0;
  float4* cA = (float4*)((char*)d_ws + off); off += (size_t)LSTEPS * CSTRIDE * 2 * sizeof(float4);
  float4* cB = (float4*)((char*)d_ws + off); off += (size_t)LSTEPS * CSTRIDE * 2 * sizeof(float4);
  unsigned short* Xr = (unsigned short*)((char*)d_ws + off); off += (size_t)MB * NF * 2;
  unsigned short* Xi = (unsigned short*)((char*)d_ws + off); off += (size_t)MB * NF * 2;
  unsigned short* Cb = (unsigned short*)((char*)d_ws + off); off += (size_t)8 * 4 * PL * 2;  // 8 chunks x [nr,ni,tr,ti]
  unsigned short* W1 = (unsigned short*)((char*)d_ws + off); off += (size_t)4 * 4 * PL * 2;
  unsigned short* W2 = (unsigned short*)((char*)d_ws + off); off += (size_t)2 * 4 * PL * 2;
  unsigned short* Uu = (unsigned short*)((char*)d_ws + off); off += (size_t)1 * 4 * PL * 2;

  prep_kernel<<<1088, 256, 0, stream>>>(a0, a1, b0, b1, (const float4*)cmplx,
                                        cA, cB, Xr, Xi);
  chunk_mesh<<<2048, 64, 0, stream>>>(cA, cB, Cb);
  // L1: W1_z = C_{2z+1} · C_{2z}   (hw 17+17 -> 34)
  prod_kernel<<<dim3(16, 8, 4), 256, 0, stream>>>(
      Cb + 2 * PL, Cb + 4 * PL, W1, 8 * PL, 8 * PL, 17, 17);
  // L2: W2_z = W1_{2z+1} · W1_{2z} (hw 34+34 -> 68)
  prod_kernel<<<dim3(16, 8, 2), 256, 0, stream>>>(
      W1 + 2 * PL, W1 + 4 * PL, W2, 8 * PL, 8 * PL, 34, 34);
  // L3: U = W2_1 · W2_0            (hw 68+68 -> 136)
  prod_kernel<<<dim3(16, 8, 1), 256, 0, stream>>>(
      W2 + 2 * PL, W2 + 4 * PL, Uu, 8 * PL, 8 * PL, 68, 68);
  cgemm_kernel<<<(MB / 32) * (NF / 64), 256, 0, stream>>>(
      Xr, Xi, Uu, Uu + PL, omega, (float2*)d_out);
}

// Round 8
// 50.253 us; speedup vs baseline: 1.2168x; 1.2168x over previous
//
#include <hip/hip_runtime.h>

#define LSTEPS 64
#define NF 512
#define MB 2048
#define CSTRIDE 256   // padded per-step pair stride for cA/cB (in float4-pairs)

typedef __attribute__((ext_vector_type(8))) short bf16x8;
typedef __attribute__((ext_vector_type(4))) float f32x4;
typedef __attribute__((ext_vector_type(4))) int i32x4;

__device__ __forceinline__ float2 cmul(float2 a, float2 b) {
  return make_float2(fmaf(a.x, b.x, -(a.y * b.y)), fmaf(a.x, b.y, a.y * b.x));
}
__device__ __forceinline__ float2 cfma(float2 a, float2 b, float2 c) {
  return make_float2(fmaf(a.x, b.x, fmaf(-a.y, b.y, c.x)),
                     fmaf(a.x, b.y, fmaf(a.y, b.x, c.y)));
}
__device__ __forceinline__ unsigned short f2bf(float f) {
  union { float f; unsigned u; } v; v.f = f;
  unsigned r = v.u + 0x7FFF + ((v.u >> 16) & 1);
  return (unsigned short)(r >> 16);
}

// ---------------- K1: coeffs (incl. zero-fill of cB pair 255) + X->bf16 planes ----------------
__global__ __launch_bounds__(256) void prep_kernel(
    const float* __restrict__ a0, const float* __restrict__ a1,
    const float* __restrict__ b0, const float* __restrict__ b1,
    const float4* __restrict__ Xf,     // (2048*512/2) float4 = 2 complex each
    float4* __restrict__ cA, float4* __restrict__ cB,
    unsigned short* __restrict__ Xr, unsigned short* __restrict__ Xi)
{
  const int bid = blockIdx.x, tid = threadIdx.x;
  if (bid < 64) {
    const int l = bid;
    {
      float ang0 = a0[l * 256 + tid], ang1 = a1[l * 256 + tid];
      float se, ce, st, ct;
      sincosf(ang0, &se, &ce);
      sincosf(ang1, &st, &ct);
      float2 ephi = make_float2(ce, se);
      float2 tt = make_float2(0.5f * (ct - 1.0f), 0.5f * st);
      float2 uu = make_float2(0.5f * (ct + 1.0f), 0.5f * st);
      float2 C1 = cmul(ephi, tt);
      float2 C2 = make_float2(-uu.y, uu.x);
      float2 eu = cmul(ephi, uu);
      float2 C3 = make_float2(-eu.y, eu.x);
      float2 C4 = make_float2(-tt.x, -tt.y);
      float4* dst = cA + (size_t)(l * CSTRIDE + tid) * 2;
      dst[0] = make_float4(C1.x, C1.y, C2.x, C2.y);
      dst[1] = make_float4(C3.x, C3.y, C4.x, C4.y);
    }
    if (tid < 255) {
      float ang0 = b0[l * 255 + tid], ang1 = b1[l * 255 + tid];
      float se, ce, st, ct;
      sincosf(ang0, &se, &ce);
      sincosf(ang1, &st, &ct);
      float2 ephi = make_float2(ce, se);
      float2 tt = make_float2(0.5f * (ct - 1.0f), 0.5f * st);
      float2 uu = make_float2(0.5f * (ct + 1.0f), 0.5f * st);
      float2 C1 = cmul(ephi, tt);
      float2 C2 = make_float2(-uu.y, uu.x);
      float2 eu = cmul(ephi, uu);
      float2 C3 = make_float2(-eu.y, eu.x);
      float2 C4 = make_float2(-tt.x, -tt.y);
      float4* dst = cB + (size_t)(l * CSTRIDE + tid) * 2;
      dst[0] = make_float4(C1.x, C1.y, C2.x, C2.y);
      dst[1] = make_float4(C3.x, C3.y, C4.x, C4.y);
    } else {
      // zero-fill the padded B pair 255 so NO read in the chain is ever unwritten
      float4* dst = cB + (size_t)(l * CSTRIDE + 255) * 2;
      dst[0] = make_float4(0.f, 0.f, 0.f, 0.f);
      dst[1] = make_float4(0.f, 0.f, 0.f, 0.f);
    }
  } else {
    // X (float2) -> bf16 planes: 1024 blocks x 256 thr, 1 quad (4 complex) each
    const int qi = (bid - 64) * 256 + tid;       // 0..262143
    float4 v0 = Xf[(size_t)qi * 2];
    float4 v1 = Xf[(size_t)qi * 2 + 1];
    ushort4 r, im;
    r.x = f2bf(v0.x); im.x = f2bf(v0.y);
    r.y = f2bf(v0.z); im.y = f2bf(v0.w);
    r.z = f2bf(v1.x); im.z = f2bf(v1.y);
    r.w = f2bf(v1.z); im.w = f2bf(v1.w);
    *(ushort4*)(Xr + (size_t)qi * 4) = r;
    *(ushort4*)(Xi + (size_t)qi * 4) = im;
  }
}

// ---------------- K2: banded mesh, 2 columns per wave, full-column writes ----------------
// __launch_bounds__(64, 1): 1 wave/EU minimum -> VGPR budget up to 512. The 3-bank
// coefficient pipeline + 2 column states needs ~160 VGPR; without this the compiler
// caps VGPRs for occupancy and spills them to scratch INSIDE the 64-step serial loop.
struct MZS { float2 a0, b0, a1, b1; };

__device__ __forceinline__ void mzi_apply(const float4& k0, const float4& k1,
                                          float2& a, float2& b) {
  float2 c1 = make_float2(k0.x, k0.y), c2 = make_float2(k0.z, k0.w);
  float2 c3 = make_float2(k1.x, k1.y), c4 = make_float2(k1.z, k1.w);
  float2 na = cfma(c2, b, cmul(c1, a));
  float2 nb = cfma(c4, b, cmul(c3, a));
  a = na; b = nb;
}
// boundary B-MZI: a updated only if en; returns (en ? nb : 0)
__device__ __forceinline__ float2 mzi_bnd(const float4& k0, const float4& k1,
                                          float2& a, float2 b, bool en) {
  float2 d1 = make_float2(k0.x, k0.y), d2 = make_float2(k0.z, k0.w);
  float2 d3 = make_float2(k1.x, k1.y), d4 = make_float2(k1.z, k1.w);
  float2 na = cfma(d2, b, cmul(d1, a));
  float2 nb = cfma(d4, b, cmul(d3, a));
  if (en) a = na;
  return en ? nb : make_float2(0.f, 0.f);
}

__device__ __forceinline__ void load_bank(float4 (&K)[8],
    const float4* __restrict__ cA, const float4* __restrict__ cB, int l, int q0)
{
  const float4* pa = cA + (size_t)l * (CSTRIDE * 2) + (size_t)q0 * 2;
  const float4* pb = cB + (size_t)l * (CSTRIDE * 2) + (size_t)q0 * 2;
  K[0] = pa[0]; K[1] = pa[1]; K[2] = pa[2]; K[3] = pa[3];
  K[4] = pb[0]; K[5] = pb[1]; K[6] = pb[2]; K[7] = pb[3];
}

__device__ __forceinline__ void step_state(const float4 (&K)[8], int L, bool hasBnd,
                                           MZS& s)
{
  mzi_apply(K[0], K[1], s.a0, s.b0);          // layer A, pair q0
  mzi_apply(K[2], K[3], s.a1, s.b1);          // layer A, pair q1
  float xnx = __shfl_down(s.a0.x, 1);         // neighbor's post-A a0 (pair q1+1)
  float xny = __shfl_down(s.a0.y, 1);
  float2 xn = (L == 63) ? make_float2(0.f, 0.f) : make_float2(xnx, xny);
  float2 nbo = mzi_bnd(K[6], K[7], s.b1, xn, hasBnd);   // boundary B, pair q1
  mzi_apply(K[4], K[5], s.b0, s.a1);          // internal B, pair q0
  float px = __shfl_up(nbo.x, 1);
  float py = __shfl_up(nbo.y, 1);
  if (L > 0) s.a0 = make_float2(px, py);
}

__global__ __launch_bounds__(64, 1) void mesh_kernel(
    const float4* __restrict__ cA, const float4* __restrict__ cB,
    unsigned short* __restrict__ Ur, unsigned short* __restrict__ Ui)
{
  const int bid = blockIdx.x;
  const int c = (bid & 7) * 32 + (bid >> 3);   // bijective XCD swizzle (256 = 8*32)
  const int L = threadIdx.x;
  // columns j0=2c, j1=2c+1 share impulse pair p0=c -> same window
  int ws = c - 63; ws = ws < 0 ? 0 : (ws > 128 ? 128 : ws);
  const int q0 = ws + 2 * L, q1 = q0 + 1;
  const bool hasBnd = (q1 < 255);

  MZS s0, s1;   // state for column j0 (impulse at row 2c) and j1 (row 2c+1)
  s0.a0 = make_float2((q0 == c) ? 1.f : 0.f, 0.f);
  s0.b0 = make_float2(0.f, 0.f);
  s0.a1 = make_float2((q1 == c) ? 1.f : 0.f, 0.f);
  s0.b1 = make_float2(0.f, 0.f);
  s1.a0 = make_float2(0.f, 0.f);
  s1.b0 = make_float2((q0 == c) ? 1.f : 0.f, 0.f);
  s1.a1 = make_float2(0.f, 0.f);
  s1.b1 = make_float2((q1 == c) ? 1.f : 0.f, 0.f);

  float4 K0[8], K1[8], K2[8];
  load_bank(K0, cA, cB, 0, q0);
  load_bank(K1, cA, cB, 1, q0);
  load_bank(K2, cA, cB, 2, q0);

#pragma unroll 1
  for (int l = 0; l < 63; l += 3) {
    step_state(K0, L, hasBnd, s0); step_state(K0, L, hasBnd, s1);
    load_bank(K0, cA, cB, (l + 3 < 64) ? l + 3 : 63, q0);
    step_state(K1, L, hasBnd, s0); step_state(K1, L, hasBnd, s1);
    load_bank(K1, cA, cB, (l + 4 < 64) ? l + 4 : 63, q0);
    step_state(K2, L, hasBnd, s0); step_state(K2, L, hasBnd, s1);
    load_bank(K2, cA, cB, (l + 5 < 64) ? l + 5 : 63, q0);
  }
  step_state(K0, L, hasBnd, s0); step_state(K0, L, hasBnd, s1);   // step 63

  // ---- write the FULL columns j0,j1 (packed 4B stores): in-window values + zeros ----
  unsigned* Ur32 = (unsigned*)Ur;
  unsigned* Ui32 = (unsigned*)Ui;
  const int rows[4] = {2 * q0, 2 * q0 + 1, 2 * q1, 2 * q1 + 1};
  const float2 v0[4] = {s0.a0, s0.b0, s0.a1, s0.b1};
  const float2 v1[4] = {s1.a0, s1.b0, s1.a1, s1.b1};
#pragma unroll
  for (int e = 0; e < 4; ++e) {
    unsigned pr = (unsigned)f2bf(v0[e].x) | ((unsigned)f2bf(v1[e].x) << 16);
    unsigned pi = (unsigned)f2bf(v0[e].y) | ((unsigned)f2bf(v1[e].y) << 16);
    Ur32[(size_t)rows[e] * (NF / 2) + c] = pr;
    Ui32[(size_t)rows[e] * (NF / 2) + c] = pi;
  }
#pragma unroll
  for (int e = 0; e < 4; ++e) {
    const int row = (2 * ws + 256 + 4 * L + e) & 511;   // the 256 out-of-window rows
    Ur32[(size_t)row * (NF / 2) + c] = 0u;
    Ui32[(size_t)row * (NF / 2) + c] = 0u;
  }
}

// ---------------- K3: banded complex GEMM, BM=32 -> 512 blocks ----------------
#define BMT 32
#define BNT 64
#define LDT 72   // pad 64->72 bf16

__global__ __launch_bounds__(256) void cgemm_kernel(
    const unsigned short* __restrict__ Xr, const unsigned short* __restrict__ Xi,
    const unsigned short* __restrict__ Ur, const unsigned short* __restrict__ Ui,
    const float* __restrict__ omega,
    float2* __restrict__ Y)
{
  __shared__ __align__(16) unsigned short Ars[BMT][LDT];
  __shared__ __align__(16) unsigned short Ais[BMT][LDT];
  __shared__ __align__(16) unsigned short Brs[BNT][LDT];
  __shared__ __align__(16) unsigned short Bis[BNT][LDT];

  const int tid = threadIdx.x;
  const int w = tid >> 6;
  const int wm = w & 1;            // m-half (16 rows)
  const int wn = w >> 1;           // n-half (32 cols)
  const int lane = tid & 63;
  const int bm = (blockIdx.x >> 3) * BMT;   // 64 m-tiles
  const int bn = (blockIdx.x & 7) * BNT;    // 8 n-tiles

  int klo = bn - 132; klo = klo < 0 ? 0 : klo; klo &= ~63;
  int khi = bn + 196; khi = khi > NF ? NF : khi; khi = (khi + 63) & ~63;

  f32x4 acc_r[2], acc_i[2];
#pragma unroll
  for (int nf = 0; nf < 2; ++nf) {
    acc_r[nf] = (f32x4){0.f, 0.f, 0.f, 0.f};
    acc_i[nf] = (f32x4){0.f, 0.f, 0.f, 0.f};
  }

  const int sar = tid >> 3, sak = (tid & 7) * 8;
  const int sbr = tid >> 2, sbk = (tid & 3) * 16;

  for (int k0 = klo; k0 < khi; k0 += 64) {
    const uint4* gar = (const uint4*)(Xr + (size_t)(bm + sar) * NF + k0 + sak);
    const uint4* gai = (const uint4*)(Xi + (size_t)(bm + sar) * NF + k0 + sak);
    const uint4* gbr = (const uint4*)(Ur + (size_t)(bn + sbr) * NF + k0 + sbk);
    const uint4* gbi = (const uint4*)(Ui + (size_t)(bn + sbr) * NF + k0 + sbk);
    uint4 ar = gar[0];
    uint4 ai = gai[0];
    uint4 br0 = gbr[0], br1 = gbr[1];
    uint4 bi0 = gbi[0], bi1 = gbi[1];

    if (k0 > klo) __syncthreads();

    *(uint4*)&Ars[sar][sak]     = ar;
    *(uint4*)&Ais[sar][sak]     = ai;
    *(uint4*)&Brs[sbr][sbk]     = br0;
    *(uint4*)&Brs[sbr][sbk + 8] = br1;
    *(uint4*)&Bis[sbr][sbk]     = bi0;
    *(uint4*)&Bis[sbr][sbk + 8] = bi1;

    __syncthreads();

#pragma unroll
    for (int kk = 0; kk < 2; ++kk) {
      const int ko = kk * 32 + (lane >> 4) * 8;
      bf16x8 afr = *(const bf16x8*)&Ars[wm * 16 + (lane & 15)][ko];
      bf16x8 afi = *(const bf16x8*)&Ais[wm * 16 + (lane & 15)][ko];
      i32x4 neg = (i32x4)afi ^ (int)0x80008000;
      bf16x8 afin = (bf16x8)neg;     // -Ai
#pragma unroll
      for (int nf = 0; nf < 2; ++nf) {
        bf16x8 bfr = *(const bf16x8*)&Brs[wn * 32 + nf * 16 + (lane & 15)][ko];
        bf16x8 bfi = *(const bf16x8*)&Bis[wn * 32 + nf * 16 + (lane & 15)][ko];
        acc_r[nf] = __builtin_amdgcn_mfma_f32_16x16x32_bf16(afr,  bfr, acc_r[nf], 0, 0, 0);
        acc_r[nf] = __builtin_amdgcn_mfma_f32_16x16x32_bf16(afin, bfi, acc_r[nf], 0, 0, 0);
        acc_i[nf] = __builtin_amdgcn_mfma_f32_16x16x32_bf16(afr,  bfi, acc_i[nf], 0, 0, 0);
        acc_i[nf] = __builtin_amdgcn_mfma_f32_16x16x32_bf16(afi,  bfr, acc_i[nf], 0, 0, 0);
      }
    }
  }

  const int dn0 = bn + wn * 32 + (lane & 15);
  const int dm0 = bm + wm * 16 + (lane >> 4) * 4;
#pragma unroll
  for (int nf = 0; nf < 2; ++nf) {
    const int n = dn0 + nf * 16;
    float sn, cn;
    sincosf(omega[n], &sn, &cn);
#pragma unroll
    for (int r = 0; r < 4; ++r) {
      float yr = acc_r[nf][r], yi = acc_i[nf][r];
      Y[(size_t)(dm0 + r) * NF + n] =
          make_float2(fmaf(yr, cn, -(yi * sn)), fmaf(yr, sn, yi * cn));
    }
  }
}

extern "C" void kernel_launch(void* const* d_in, const int* in_sizes, int n_in,
                              void* d_out, int out_size, void* d_ws, size_t ws_size,
                              hipStream_t stream) {
  const float* cmplx = (const float*)d_in[0];   // (2048, 512, 2) f32
  const float* a0    = (const float*)d_in[1];
  const float* a1    = (const float*)d_in[2];
  const float* b0    = (const float*)d_in[3];
  const float* b1    = (const float*)d_in[4];
  const float* omega = (const float*)d_in[5];

  size_t off = 0;
  float4* cA = (float4*)((char*)d_ws + off); off += (size_t)LSTEPS * CSTRIDE * 2 * sizeof(float4);
  float4* cB = (float4*)((char*)d_ws + off); off += (size_t)LSTEPS * CSTRIDE * 2 * sizeof(float4);
  unsigned short* Ur = (unsigned short*)((char*)d_ws + off); off += (size_t)NF * NF * 2;
  unsigned short* Ui = (unsigned short*)((char*)d_ws + off); off += (size_t)NF * NF * 2;
  unsigned short* Xr = (unsigned short*)((char*)d_ws + off); off += (size_t)MB * NF * 2;
  unsigned short* Xi = (unsigned short*)((char*)d_ws + off); off += (size_t)MB * NF * 2;

  prep_kernel<<<1088, 256, 0, stream>>>(a0, a1, b0, b1, (const float4*)cmplx,
                                        cA, cB, Xr, Xi);
  mesh_kernel<<<256, 64, 0, stream>>>(cA, cB, Ur, Ui);
  cgemm_kernel<<<(MB / BMT) * (NF / BNT), 256, 0, stream>>>(
      Xr, Xi, Ur, Ui, omega, (float2*)d_out);
}